// Round 2
// baseline (240.931 us; speedup 1.0000x reference)
//
#include <hip/hip_runtime.h>
#include <hip/hip_fp16.h>
#include <math.h>

// Problem constants
#define B_  8192
#define F_  32
#define V_  64
#define C_  32
#define KP_ 7
#define EPS_ 1e-6f

// ws layout (floats):
//  [0,248)           : w[f][k]  (31 x 8 gumbel-softmax weights); [248,256) zeros (pad weight slot)
//  [256,288)         : offc[c]
//  [288,488)         : etab[200] (ints): packed (widx<<20)|(fk<<12)|(fi<<6)|ci, 25 per q
//  [512,66048)       : G[j][v][c]   (folded t0/self/pair-lse table, 256 KB)
//  [66048,510464)    : lse[fk][xc][c]  (1.78 MB)
//  byte 8MB..8MB+56.9MB : fp16 shadow of pair_tables (written by lse pass, gathered by main)
#define WS_OFF  256
#define WS_ETAB 288
#define WS_G    512
#define WS_LSE  66048
#define WS_H    2097152ull                         // float offset == byte offset 8 MB
#define H_BYTES (217ull * V_ * V_ * C_ * 2ull)     // 56,885,248 B
#define NEED_WS (WS_H * 4ull + H_BYTES)            // ~65.3 MB

// lse worker decomposition: 217*64*8 = 111104 float4 outputs, 64 per block,
// 4-way split of the 64-deep a-reduction -> 256 threads/block, 1736 blocks.
#define NBLK_LSE 1736

__device__ const int d_split[9] = {0, 25, 50, 74, 99, 123, 148, 172, 196};

// ---- Kernel A (fused): blocks 0..1735 = lse over pair self-axis (+fp16
//      shadow write when CVT), 4-way split a-reduction for occupancy;
//      block 1736 = prep (weights/etab/offc), hides under the BW-bound pass.
template<int CVT>
__global__ __launch_bounds__(256)
void lse_prep_kernel(const float* __restrict__ pt,
                     const float* __restrict__ cl, const float* __restrict__ t0,
                     const float* __restrict__ st, const float* __restrict__ sl,
                     const float* __restrict__ un, float* __restrict__ ws) {
    if (blockIdx.x < NBLK_LSE) {
        __shared__ float4 red[3][64];
        int tid  = threadIdx.x;
        int part = tid >> 6;          // 0..3: which 16-slice of the a-axis
        int lane = tid & 63;
        int idx  = blockIdx.x * 64 + lane;           // (fk, v, c4) output id
        int c4 = idx & 7, v = (idx >> 3) & 63, fk = idx >> 9;   // fk 0..216
        size_t eoff = (size_t)fk * (V_ * V_ * C_) + v * C_ + c4 * 4
                    + (size_t)(part * 16) * (V_ * C_);
        const float* p = pt + eoff;
        __half* ph = (__half*)(ws + WS_H) + eoff;
        float4 s = make_float4(0.f, 0.f, 0.f, 0.f);
        #pragma unroll
        for (int a = 0; a < 16; a += 8) {
            float4 l[8];
            #pragma unroll
            for (int i = 0; i < 8; i++)
                l[i] = *(const float4*)(p + (size_t)(a + i) * (V_ * C_));
            if (CVT) {
                // fp16 shadow: same index order as pt, halves instead of floats
                #pragma unroll
                for (int i = 0; i < 8; i++) {
                    union { __half2 h; unsigned u; } ha, hb;
                    ha.h = __floats2half2_rn(l[i].x, l[i].y);
                    hb.h = __floats2half2_rn(l[i].z, l[i].w);
                    *(uint2*)(ph + (size_t)(a + i) * (V_ * C_)) = make_uint2(ha.u, hb.u);
                }
            }
            #pragma unroll
            for (int i = 0; i < 8; i++) {
                s.x += __expf(l[i].x); s.y += __expf(l[i].y);
                s.z += __expf(l[i].z); s.w += __expf(l[i].w);
            }
        }
        if (part) red[part - 1][lane] = s;
        __syncthreads();
        if (part == 0) {
            #pragma unroll
            for (int pp = 0; pp < 3; pp++) {
                float4 t = red[pp][lane];
                s.x += t.x; s.y += t.y; s.z += t.z; s.w += t.w;
            }
            float4 r;
            r.x = __logf(s.x); r.y = __logf(s.y);
            r.z = __logf(s.z); r.w = __logf(s.w);
            ((float4*)(ws + WS_LSE))[idx] = r;
        }
    } else {
        // ---- prep (256 threads) ----
        __shared__ float gl[31][8];
        __shared__ float wsm[31][8];
        __shared__ float lsf[31][32];
        int tid = threadIdx.x;
        if (tid < 248) {
            int f = tid >> 3, k = tid & 7;
            int kmax = min(f + 1, KP_);
            bool valid = (k <= kmax);
            float u = un[tid];
            float g = -__logf(-__logf(u + EPS_) + EPS_);
            gl[f][k] = valid ? (sl[tid] + g) : -INFINITY;
        } else {
            ws[tid] = 0.f;   // zero pad weight slots 248..255
        }
        if (tid < 200) {
            int q = tid / 25, i = tid % 25;
            int g = d_split[q] + i;
            int packed;
            if (g < d_split[q + 1]) {
                int f = 0, base = 0;
                for (;;) { int cnt = min(f + 1, KP_); if (g < base + cnt) break; base += cnt; f++; }
                int k = g - base;
                packed = ((f * 8 + k + 1) << 20) | ((f * KP_ + k) << 12) | ((f + 1) << 6) | (f - k);
            } else {
                packed = (248 << 20);   // weight=0 pad entry
            }
            ((int*)ws)[WS_ETAB + tid] = packed;
        }
        __syncthreads();
        if (tid < 248) {
            int f = tid >> 3, k = tid & 7;
            float m = -INFINITY;
            #pragma unroll
            for (int j = 0; j < 8; j++) m = fmaxf(m, gl[f][j]);
            float s = 0.f;
            #pragma unroll
            for (int j = 0; j < 8; j++) s += __expf(gl[f][j] - m);
            float wv = __expf(gl[f][k] - m) / s;
            wsm[f][k] = wv;
            ws[tid] = wv;
        }
        for (int i = tid; i < 992; i += 256) {   // lse over self_tables v-axis
            int f = i >> 5, c = i & 31;
            float s = 0.f;
            #pragma unroll 8
            for (int v = 0; v < V_; v++) s += __expf(st[(f * V_ + v) * C_ + c]);
            lsf[f][c] = __logf(s);
        }
        __syncthreads();
        if (tid < 32) {
            int c = tid;
            float scl = 0.f;
            #pragma unroll
            for (int j = 0; j < C_; j++) scl += __expf(cl[j]);
            float lse_cl = __logf(scl);
            float s0 = 0.f;
            #pragma unroll 8
            for (int v = 0; v < V_; v++) s0 += __expf(t0[v * C_ + c]);
            float lse_t0 = __logf(s0);
            float acc = cl[c] - lse_cl - lse_t0;
            for (int f = 0; f < 31; f++) acc -= wsm[f][0] * lsf[f][c];
            ws[WS_OFF + c] = acc;
        }
    }
}

// ------------- Kernel B2: fold lse + t0 + self into G, float4 ---------------
__global__ __launch_bounds__(256)
void foldg_kernel(const float* __restrict__ t0, const float* __restrict__ st,
                  float* __restrict__ ws) {
    int idx = blockIdx.x * 256 + threadIdx.x;
    int c4 = idx & 7, v = (idx >> 3) & 63, j = idx >> 9;    // j 0..31
    int nk = min(KP_, 31 - j);
    const float4* lse4 = (const float4*)(ws + WS_LSE);
    float4 g;
    if (j == 0) {
        g = ((const float4*)t0)[v * 8 + c4];
    } else {
        float w0 = ws[(j - 1) * 8];
        float4 sv = ((const float4*)st)[((j - 1) * V_ + v) * 8 + c4];
        g.x = w0 * sv.x; g.y = w0 * sv.y; g.z = w0 * sv.z; g.w = w0 * sv.w;
    }
    for (int k = 0; k < nk; k++) {
        int f = j + k;
        float wv = ws[f * 8 + k + 1];
        float4 lv = lse4[((f * KP_ + k) * V_ + v) * 8 + c4];
        g.x -= wv * lv.x; g.y -= wv * lv.y; g.z -= wv * lv.z; g.w -= wv * lv.w;
    }
    ((float4*)(ws + WS_G))[idx] = g;
}

// ------------------------- Kernel C: main gather ----------------------------
// block = 256 threads = 8 q x 4 rows x 8 c4; grid = 2048 blocks
// CVT=1: pair gathers hit the fp16 shadow (64 B = 1 cache line per entry).
template<int CVT>
__global__ __launch_bounds__(256)
void main_kernel(const int* __restrict__ x, const float* __restrict__ pt,
                 const float* __restrict__ ws, float* __restrict__ out) {
    __shared__ int   xsh[4 * 33];      // 4 rows, stride 33 (bank spread)
    __shared__ float wsh[256];
    __shared__ int   etab[200];
    __shared__ float4 offv[8];
    __shared__ float4 part[7][32];
    int tid = threadIdx.x;
    if (tid < 128) xsh[(tid >> 5) * 33 + (tid & 31)] = x[blockIdx.x * 128 + tid];
    wsh[tid] = ws[tid];
    if (tid < 200) etab[tid] = ((const int*)ws)[WS_ETAB + tid];
    if (tid < 8)   offv[tid] = ((const float4*)(ws + WS_OFF))[tid];
    __syncthreads();

    const float4* __restrict__ G4  = (const float4*)(ws + WS_G);
    const __half* __restrict__ pth = (const __half*)(ws + WS_H);
    int q  = tid >> 5;
    int r  = (tid >> 3) & 3;
    int c4 = tid & 7;
    const int* xrow = &xsh[r * 33];
    float4 acc = make_float4(0.f, 0.f, 0.f, 0.f);

    // G part: 4 j's per q (L2-resident 256 KB table)
    #pragma unroll
    for (int jj = 0; jj < 4; jj++) {
        int j = q * 4 + jj;
        float4 gv = G4[(j * V_ + xrow[j]) * 8 + c4];
        acc.x += gv.x; acc.y += gv.y; acc.z += gv.z; acc.w += gv.w;
    }
    if (q == 0) {
        float4 ov = offv[c4];
        acc.x += ov.x; acc.y += ov.y; acc.z += ov.z; acc.w += ov.w;
    }

    // pair part: 25 table entries per q, chunks of 5 for ILP
    int beg = q * 25;
    #pragma unroll
    for (int ch = 0; ch < 5; ch++) {
        if (CVT) {
            uint2  hv[5];
            float  wt[5];
            #pragma unroll
            for (int i = 0; i < 5; i++) {
                int pk = etab[beg + ch * 5 + i];
                int ci = pk & 63, fi = (pk >> 6) & 63;
                int fk = (pk >> 12) & 255, widx = (pk >> 20) & 255;
                int xv = xrow[fi], xc = xrow[ci];
                hv[i] = *(const uint2*)(pth + ((size_t)(fk * V_ + xv) * V_ + xc) * C_ + c4 * 4);
                wt[i] = wsh[widx];
            }
            #pragma unroll
            for (int i = 0; i < 5; i++) {
                union { unsigned u; __half2 h; } a, b;
                a.u = hv[i].x; b.u = hv[i].y;
                float2 f0 = __half22float2(a.h);
                float2 f1 = __half22float2(b.h);
                acc.x += wt[i] * f0.x; acc.y += wt[i] * f0.y;
                acc.z += wt[i] * f1.x; acc.w += wt[i] * f1.y;
            }
        } else {
            float4 pv[5];
            float  wt[5];
            #pragma unroll
            for (int i = 0; i < 5; i++) {
                int pk = etab[beg + ch * 5 + i];
                int ci = pk & 63, fi = (pk >> 6) & 63;
                int fk = (pk >> 12) & 255, widx = (pk >> 20) & 255;
                int xv = xrow[fi], xc = xrow[ci];
                pv[i] = *(const float4*)(pt + ((size_t)(fk * V_ + xv) * V_ + xc) * C_ + c4 * 4);
                wt[i] = wsh[widx];
            }
            #pragma unroll
            for (int i = 0; i < 5; i++) {
                acc.x += wt[i] * pv[i].x; acc.y += wt[i] * pv[i].y;
                acc.z += wt[i] * pv[i].z; acc.w += wt[i] * pv[i].w;
            }
        }
    }

    // combine 8 q-partials
    if (q > 0) part[q - 1][r * 8 + c4] = acc;
    __syncthreads();
    if (q == 0) {
        #pragma unroll
        for (int p = 0; p < 7; p++) {
            float4 pv = part[p][r * 8 + c4];
            acc.x += pv.x; acc.y += pv.y; acc.z += pv.z; acc.w += pv.w;
        }
        ((float4*)out)[(blockIdx.x * 4 + r) * 8 + c4] = acc;
    }
}

extern "C" void kernel_launch(void* const* d_in, const int* in_sizes, int n_in,
                              void* d_out, int out_size, void* d_ws, size_t ws_size,
                              hipStream_t stream) {
    const int*   x   = (const int*)  d_in[0];
    // d_in[1] = training (unused)
    const float* cl  = (const float*)d_in[2];
    const float* t0  = (const float*)d_in[3];
    const float* st  = (const float*)d_in[4];
    const float* pt  = (const float*)d_in[5];
    const float* sl  = (const float*)d_in[6];
    const float* un  = (const float*)d_in[7];
    // d_in[8] cond_index, d_in[9] valid_mask: deterministic, computed analytically
    float* ws  = (float*)d_ws;
    float* out = (float*)d_out;

    if (ws_size >= NEED_WS) {
        // fp16-shadow path: lse pass reads pt once anyway, emits half copy
        lse_prep_kernel<1><<<NBLK_LSE + 1, 256, 0, stream>>>(pt, cl, t0, st, sl, un, ws);
        foldg_kernel<<<64, 256, 0, stream>>>(t0, st, ws);
        main_kernel<1><<<2048, 256, 0, stream>>>(x, pt, ws, out);
    } else {
        // fallback: verified f32 gather path
        lse_prep_kernel<0><<<NBLK_LSE + 1, 256, 0, stream>>>(pt, cl, t0, st, sl, un, ws);
        foldg_kernel<<<64, 256, 0, stream>>>(t0, st, ws);
        main_kernel<0><<<2048, 256, 0, stream>>>(x, pt, ws, out);
    }
}

// Round 3
// 233.581 us; speedup vs baseline: 1.0315x; 1.0315x over previous
//
#include <hip/hip_runtime.h>
#include <math.h>

// Problem constants
#define B_  8192
#define F_  32
#define V_  64
#define C_  32
#define KP_ 7
#define EPS_ 1e-6f

// ws layout (floats):
//  [0,248)           : w[f][k]  (31 x 8 gumbel-softmax weights); [248,256) zeros (pad weight slot)
//  [256,288)         : offc[c]
//  [288,488)         : etab[200] (ints): packed (widx<<20)|(fk<<12)|(fi<<6)|ci, 25 per q
//  [512,66048)       : G[j][v][c]   (folded t0/self/pair-lse table, 256 KB)
//  [66048,954880)    : partial exp-sums, 2 banks of [fk][xc][c] (217*64*32 floats each);
//                      foldg does log(bank0+bank1)
#define WS_OFF  256
#define WS_ETAB 288
#define WS_G    512
#define WS_LSE  66048
#define LSE_BANK4 111104    // bank stride in float4 units (217*64*8)

__device__ const int d_split[9] = {0, 25, 50, 74, 99, 123, 148, 172, 196};

// ---- Kernel A (fused): blocks 0..433 = exp-sum over pair self-axis.
// Block = (fk, a-half). The reduction axis (stride-8KB) is the OUTER loop;
// each block streams its 256 KB of pt contiguously, accumulating in
// registers (thread t owns slice columns [4t,4t+4) and [1024+4t,1024+4t+4)).
// No stores inside the loop -> no store-retire serialization (the round-1/2
// failure mode: VGPR=32, fp16 stores interleaved, ~2.4 TB/s flat).
// Block 434 = prep (weights/etab/offc), hides under the BW-bound pass.
__global__ __launch_bounds__(256)
void lse_prep_kernel(const float* __restrict__ pt,
                     const float* __restrict__ cl, const float* __restrict__ t0,
                     const float* __restrict__ st, const float* __restrict__ sl,
                     const float* __restrict__ un, float* __restrict__ ws) {
    if (blockIdx.x < 434) {
        int fk   = blockIdx.x >> 1;     // 0..216
        int half = blockIdx.x & 1;      // which 32-slice of the a-axis
        int t    = threadIdx.x;
        // base of this block's contiguous 256 KB region, in float4 units
        const float4* __restrict__ p =
            (const float4*)(pt + (size_t)fk * (V_ * V_ * C_)
                               + (size_t)half * 32 * (V_ * C_));
        const float4* p0 = p + t;          // column j = 4t   of each a-slice
        const float4* p1 = p + 256 + t;    // column j = 1024+4t
        float4 s0 = make_float4(0.f, 0.f, 0.f, 0.f);
        float4 s1 = make_float4(0.f, 0.f, 0.f, 0.f);
        #pragma unroll 4
        for (int a = 0; a < 32; a++) {     // a-slice stride = 2048 floats = 512 float4
            float4 l0 = p0[a * 512];
            float4 l1 = p1[a * 512];
            s0.x += __expf(l0.x); s0.y += __expf(l0.y);
            s0.z += __expf(l0.z); s0.w += __expf(l0.w);
            s1.x += __expf(l1.x); s1.y += __expf(l1.y);
            s1.z += __expf(l1.z); s1.w += __expf(l1.w);
        }
        // partial sums; foldg combines banks with log(b0+b1).
        float4* lseP = (float4*)(ws + WS_LSE) + (size_t)half * LSE_BANK4;
        lseP[fk * 512 + t]       = s0;
        lseP[fk * 512 + 256 + t] = s1;
    } else {
        // ---- prep (256 threads) ----
        __shared__ float gl[31][8];
        __shared__ float wsm[31][8];
        __shared__ float lsf[31][32];
        int tid = threadIdx.x;
        if (tid < 248) {
            int f = tid >> 3, k = tid & 7;
            int kmax = min(f + 1, KP_);
            bool valid = (k <= kmax);
            float u = un[tid];
            float g = -__logf(-__logf(u + EPS_) + EPS_);
            gl[f][k] = valid ? (sl[tid] + g) : -INFINITY;
        } else {
            ws[tid] = 0.f;   // zero pad weight slots 248..255
        }
        if (tid < 200) {
            int q = tid / 25, i = tid % 25;
            int g = d_split[q] + i;
            int packed;
            if (g < d_split[q + 1]) {
                int f = 0, base = 0;
                for (;;) { int cnt = min(f + 1, KP_); if (g < base + cnt) break; base += cnt; f++; }
                int k = g - base;
                packed = ((f * 8 + k + 1) << 20) | ((f * KP_ + k) << 12) | ((f + 1) << 6) | (f - k);
            } else {
                packed = (248 << 20);   // weight=0 pad entry
            }
            ((int*)ws)[WS_ETAB + tid] = packed;
        }
        __syncthreads();
        if (tid < 248) {
            int f = tid >> 3, k = tid & 7;
            float m = -INFINITY;
            #pragma unroll
            for (int j = 0; j < 8; j++) m = fmaxf(m, gl[f][j]);
            float s = 0.f;
            #pragma unroll
            for (int j = 0; j < 8; j++) s += __expf(gl[f][j] - m);
            float wv = __expf(gl[f][k] - m) / s;
            wsm[f][k] = wv;
            ws[tid] = wv;
        }
        for (int i = tid; i < 992; i += 256) {   // lse over self_tables v-axis
            int f = i >> 5, c = i & 31;
            float s = 0.f;
            #pragma unroll 8
            for (int v = 0; v < V_; v++) s += __expf(st[(f * V_ + v) * C_ + c]);
            lsf[f][c] = __logf(s);
        }
        __syncthreads();
        if (tid < 32) {
            int c = tid;
            float scl = 0.f;
            #pragma unroll
            for (int j = 0; j < C_; j++) scl += __expf(cl[j]);
            float lse_cl = __logf(scl);
            float s0 = 0.f;
            #pragma unroll 8
            for (int v = 0; v < V_; v++) s0 += __expf(t0[v * C_ + c]);
            float lse_t0 = __logf(s0);
            float acc = cl[c] - lse_cl - lse_t0;
            for (int f = 0; f < 31; f++) acc -= wsm[f][0] * lsf[f][c];
            ws[WS_OFF + c] = acc;
        }
    }
}

// ------------- Kernel B2: fold lse + t0 + self into G, float4 ---------------
// lse region now holds 2 partial-sum banks -> log(b0+b1) here (each element
// is consumed exactly once, so the log costs nothing extra).
__global__ __launch_bounds__(256)
void foldg_kernel(const float* __restrict__ t0, const float* __restrict__ st,
                  float* __restrict__ ws) {
    int idx = blockIdx.x * 256 + threadIdx.x;
    int c4 = idx & 7, v = (idx >> 3) & 63, j = idx >> 9;    // j 0..31
    int nk = min(KP_, 31 - j);
    const float4* lse4 = (const float4*)(ws + WS_LSE);
    float4 g;
    if (j == 0) {
        g = ((const float4*)t0)[v * 8 + c4];
    } else {
        float w0 = ws[(j - 1) * 8];
        float4 sv = ((const float4*)st)[((j - 1) * V_ + v) * 8 + c4];
        g.x = w0 * sv.x; g.y = w0 * sv.y; g.z = w0 * sv.z; g.w = w0 * sv.w;
    }
    for (int k = 0; k < nk; k++) {
        int f = j + k;
        float wv = ws[f * 8 + k + 1];
        int iq = ((f * KP_ + k) * V_ + v) * 8 + c4;
        float4 sa = lse4[iq];
        float4 sb = lse4[LSE_BANK4 + iq];
        g.x -= wv * __logf(sa.x + sb.x);
        g.y -= wv * __logf(sa.y + sb.y);
        g.z -= wv * __logf(sa.z + sb.z);
        g.w -= wv * __logf(sa.w + sb.w);
    }
    ((float4*)(ws + WS_G))[idx] = g;
}

// ------------------------- Kernel C: main gather ----------------------------
// block = 256 threads = 8 q x 4 rows x 8 c4; grid = 2048 blocks
// f32 gathers direct from pt (the round-0-verified path; fp16 shadow was a
// net loss: main is gather-count-bound, not byte-bound).
__global__ __launch_bounds__(256)
void main_kernel(const int* __restrict__ x, const float* __restrict__ pt,
                 const float* __restrict__ ws, float* __restrict__ out) {
    __shared__ int   xsh[4 * 33];      // 4 rows, stride 33 (bank spread)
    __shared__ float wsh[256];
    __shared__ int   etab[200];
    __shared__ float4 offv[8];
    __shared__ float4 part[7][32];
    int tid = threadIdx.x;
    if (tid < 128) xsh[(tid >> 5) * 33 + (tid & 31)] = x[blockIdx.x * 128 + tid];
    wsh[tid] = ws[tid];
    if (tid < 200) etab[tid] = ((const int*)ws)[WS_ETAB + tid];
    if (tid < 8)   offv[tid] = ((const float4*)(ws + WS_OFF))[tid];
    __syncthreads();

    const float4* __restrict__ G4 = (const float4*)(ws + WS_G);
    int q  = tid >> 5;
    int r  = (tid >> 3) & 3;
    int c4 = tid & 7;
    const int* xrow = &xsh[r * 33];
    float4 acc = make_float4(0.f, 0.f, 0.f, 0.f);

    // G part: 4 j's per q (L2-resident 256 KB table)
    #pragma unroll
    for (int jj = 0; jj < 4; jj++) {
        int j = q * 4 + jj;
        float4 gv = G4[(j * V_ + xrow[j]) * 8 + c4];
        acc.x += gv.x; acc.y += gv.y; acc.z += gv.z; acc.w += gv.w;
    }
    if (q == 0) {
        float4 ov = offv[c4];
        acc.x += ov.x; acc.y += ov.y; acc.z += ov.z; acc.w += ov.w;
    }

    // pair part: 25 table entries per q, chunks of 5 for ILP
    int beg = q * 25;
    #pragma unroll
    for (int ch = 0; ch < 5; ch++) {
        float4 pv[5];
        float  wt[5];
        #pragma unroll
        for (int i = 0; i < 5; i++) {
            int pk = etab[beg + ch * 5 + i];
            int ci = pk & 63, fi = (pk >> 6) & 63;
            int fk = (pk >> 12) & 255, widx = (pk >> 20) & 255;
            int xv = xrow[fi], xc = xrow[ci];
            pv[i] = *(const float4*)(pt + ((size_t)(fk * V_ + xv) * V_ + xc) * C_ + c4 * 4);
            wt[i] = wsh[widx];
        }
        #pragma unroll
        for (int i = 0; i < 5; i++) {
            acc.x += wt[i] * pv[i].x; acc.y += wt[i] * pv[i].y;
            acc.z += wt[i] * pv[i].z; acc.w += wt[i] * pv[i].w;
        }
    }

    // combine 8 q-partials
    if (q > 0) part[q - 1][r * 8 + c4] = acc;
    __syncthreads();
    if (q == 0) {
        #pragma unroll
        for (int p = 0; p < 7; p++) {
            float4 pv = part[p][r * 8 + c4];
            acc.x += pv.x; acc.y += pv.y; acc.z += pv.z; acc.w += pv.w;
        }
        ((float4*)out)[(blockIdx.x * 4 + r) * 8 + c4] = acc;
    }
}

extern "C" void kernel_launch(void* const* d_in, const int* in_sizes, int n_in,
                              void* d_out, int out_size, void* d_ws, size_t ws_size,
                              hipStream_t stream) {
    const int*   x   = (const int*)  d_in[0];
    // d_in[1] = training (unused)
    const float* cl  = (const float*)d_in[2];
    const float* t0  = (const float*)d_in[3];
    const float* st  = (const float*)d_in[4];
    const float* pt  = (const float*)d_in[5];
    const float* sl  = (const float*)d_in[6];
    const float* un  = (const float*)d_in[7];
    // d_in[8] cond_index, d_in[9] valid_mask: deterministic, computed analytically
    float* ws  = (float*)d_ws;
    float* out = (float*)d_out;

    lse_prep_kernel<<<435, 256, 0, stream>>>(pt, cl, t0, st, sl, un, ws);
    foldg_kernel<<<64, 256, 0, stream>>>(t0, st, ws);
    main_kernel<<<2048, 256, 0, stream>>>(x, pt, ws, out);
}